// Round 1
// 775.026 us; speedup vs baseline: 1.0078x; 1.0078x over previous
//
#include <hip/hip_runtime.h>
#include <hip/hip_bf16.h>

#define XDIM 128
#define YDIM 512

typedef __bf16 bf16x8 __attribute__((ext_vector_type(8)));
typedef float  floatx4 __attribute__((ext_vector_type(4)));

// ---------------------------------------------------------------------------
// Prep kernel: one-shot conversion of W (f32 [512][128]) into bf16 W and bf16
// W*W in the workspace. Removes the per-block re-conversion of all 64K W
// elements that the previous kernel did 4096 times (dominant VALU cost).
// 8192 threads x 8 elements, float4 loads, bf16x8 (16B) stores.
// ---------------------------------------------------------------------------
__global__ __launch_bounds__(256)
void prep_w_kernel(const float* __restrict__ W,
                   __bf16* __restrict__ Wb,
                   __bf16* __restrict__ W2b)
{
    const int t = blockIdx.x * 256 + threadIdx.x;      // 32 blocks * 256 = 8192
    const float* src = W + (size_t)t * 8;
    floatx4 a = *(const floatx4*)(src);
    floatx4 c = *(const floatx4*)(src + 4);
    bf16x8 w, w2;
#pragma unroll
    for (int j = 0; j < 4; ++j) {
        w[j]      = (__bf16)a[j];
        w[j + 4]  = (__bf16)c[j];
        w2[j]     = (__bf16)(a[j] * a[j]);
        w2[j + 4] = (__bf16)(c[j] * c[j]);
    }
    *(bf16x8*)(Wb  + (size_t)t * 8) = w;
    *(bf16x8*)(W2b + (size_t)t * 8) = w2;
}

// ---------------------------------------------------------------------------
// Main kernel, v2.
//  - Block: 256 threads = 4 waves; tile 32 rows x 512 cols. Wave owns 128 cols.
//  - MFMA operands SWAPPED vs v1: A = W fragment (M = y-cols), B = mean/exp
//    fragment (N = batch rows). C/D layout (m89): col=lane&15 -> batch row,
//    row=(lane>>4)*4+reg -> y-col. So each lane's floatx4 acc holds 4
//    CONSECUTIVE output columns => dwordx4 stores (32 stores/thread vs 128).
//  - W / W^2 fragments are straight bf16x8 loads from the workspace (L2-hot,
//    zero VALU).
//  - Wave's 128 cols processed in two 64-col halves so acc = 64 VGPR (reused),
//    targeting 3 blocks/CU occupancy.
// ---------------------------------------------------------------------------
__global__ __launch_bounds__(256, 3)
void decoder_mfma_v2(const float* __restrict__ mean,
                     const float* __restrict__ logvar,
                     const __bf16* __restrict__ Wb,
                     const __bf16* __restrict__ W2b,
                     const float* __restrict__ bias,
                     float* __restrict__ out_mean,
                     float* __restrict__ out_logv)
{
    const int tid   = threadIdx.x;
    const int lane  = tid & 63;
    const int wv    = tid >> 6;
    const int laneM = lane & 15;        // frag row/col index
    const int laneG = lane >> 4;        // 0..3
    const int laneK = laneG * 8;        // k-chunk base

    const int row_base = blockIdx.x * 32;
    const int col_base = wv * 128;

    // ---- batch-side (B operand) fragments: mean, exp(logvar); [rt][ks] ----
    bf16x8 bM[2][4], bV[2][4];
#pragma unroll
    for (int rt = 0; rt < 2; ++rt) {
        const int r = row_base + rt * 16 + laneM;
        const float* mrow = mean   + (size_t)r * XDIM + laneK;
        const float* lrow = logvar + (size_t)r * XDIM + laneK;
#pragma unroll
        for (int ks = 0; ks < 4; ++ks) {
            floatx4 m0 = *(const floatx4*)(mrow + ks * 32);
            floatx4 m1 = *(const floatx4*)(mrow + ks * 32 + 4);
            floatx4 l0 = *(const floatx4*)(lrow + ks * 32);
            floatx4 l1 = *(const floatx4*)(lrow + ks * 32 + 4);
            bf16x8 fm, fv;
#pragma unroll
            for (int j = 0; j < 4; ++j) {
                fm[j]     = (__bf16)m0[j];
                fm[j + 4] = (__bf16)m1[j];
                fv[j]     = (__bf16)__expf(l0[j]);
                fv[j + 4] = (__bf16)__expf(l1[j]);
            }
            bM[rt][ks] = fm;
            bV[rt][ks] = fv;
        }
    }

#pragma unroll
    for (int h = 0; h < 2; ++h) {
        floatx4 accM[2][4], accV[2][4];
#pragma unroll
        for (int rt = 0; rt < 2; ++rt)
#pragma unroll
            for (int ct = 0; ct < 4; ++ct) {
                accM[rt][ct] = (floatx4){0.f, 0.f, 0.f, 0.f};
                accV[rt][ct] = (floatx4){0.f, 0.f, 0.f, 0.f};
            }

        // ---- K-loop: A fragments are pure bf16x8 loads from workspace ----
#pragma unroll
        for (int ks = 0; ks < 4; ++ks) {
#pragma unroll
            for (int ct = 0; ct < 4; ++ct) {
                const size_t off =
                    (size_t)(col_base + h * 64 + ct * 16 + laneM) * XDIM
                    + ks * 32 + laneK;
                bf16x8 aw = *(const bf16x8*)(Wb  + off);
                bf16x8 as = *(const bf16x8*)(W2b + off);
#pragma unroll
                for (int rt = 0; rt < 2; ++rt) {
                    accM[rt][ct] = __builtin_amdgcn_mfma_f32_16x16x32_bf16(
                                       aw, bM[rt][ks], accM[rt][ct], 0, 0, 0);
                    accV[rt][ct] = __builtin_amdgcn_mfma_f32_16x16x32_bf16(
                                       as, bV[rt][ks], accV[rt][ct], 0, 0, 0);
                }
            }
        }

        // ---- epilogue: reg i = consecutive y-col -> dwordx4 stores ----
#pragma unroll
        for (int ct = 0; ct < 4; ++ct) {
            const int ybase = col_base + h * 64 + ct * 16 + laneG * 4;
            const floatx4 bv = *(const floatx4*)(bias + ybase);
#pragma unroll
            for (int rt = 0; rt < 2; ++rt) {
                const int r = row_base + rt * 16 + laneM;
                floatx4 om = accM[rt][ct] + bv;
                floatx4 ol;
#pragma unroll
                for (int i = 0; i < 4; ++i)
                    ol[i] = __logf(accV[rt][ct][i]);
                __builtin_nontemporal_store(
                    om, (floatx4*)(out_mean + (size_t)r * YDIM + ybase));
                __builtin_nontemporal_store(
                    ol, (floatx4*)(out_logv + (size_t)r * YDIM + ybase));
            }
        }
    }
}

// ---------------------------------------------------------------------------
// Fallback (previous best): used only if the workspace is too small.
// ---------------------------------------------------------------------------
__global__ __launch_bounds__(256, 2)
void decoder_mfma_kernel(const float* __restrict__ mean,
                         const float* __restrict__ logvar,
                         const float* __restrict__ W,
                         const float* __restrict__ bias,
                         float* __restrict__ out_mean,
                         float* __restrict__ out_logv)
{
    const int tid   = threadIdx.x;
    const int lane  = tid & 63;
    const int wv    = tid >> 6;
    const int laneM = lane & 15;
    const int laneK = (lane >> 4) * 8;

    const int row_base = blockIdx.x * 32;
    const int col_base = wv * 128;

    bf16x8 aM[2][4], aV[2][4];
#pragma unroll
    for (int rt = 0; rt < 2; ++rt) {
        const int r = row_base + rt * 16 + laneM;
        const float* mrow = mean   + (size_t)r * XDIM + laneK;
        const float* lrow = logvar + (size_t)r * XDIM + laneK;
#pragma unroll
        for (int ks = 0; ks < 4; ++ks) {
            floatx4 m0 = *(const floatx4*)(mrow + ks * 32);
            floatx4 m1 = *(const floatx4*)(mrow + ks * 32 + 4);
            floatx4 l0 = *(const floatx4*)(lrow + ks * 32);
            floatx4 l1 = *(const floatx4*)(lrow + ks * 32 + 4);
            bf16x8 am, av;
#pragma unroll
            for (int j = 0; j < 4; ++j) {
                am[j]     = (__bf16)m0[j];
                am[j + 4] = (__bf16)m1[j];
                av[j]     = (__bf16)__expf(l0[j]);
                av[j + 4] = (__bf16)__expf(l1[j]);
            }
            aM[rt][ks] = am;
            aV[rt][ks] = av;
        }
    }

    floatx4 accM[2][8], accV[2][8];
#pragma unroll
    for (int rt = 0; rt < 2; ++rt)
#pragma unroll
        for (int ct = 0; ct < 8; ++ct) {
            accM[rt][ct] = (floatx4){0.f, 0.f, 0.f, 0.f};
            accV[rt][ct] = (floatx4){0.f, 0.f, 0.f, 0.f};
        }

#pragma unroll
    for (int ks = 0; ks < 4; ++ks) {
#pragma unroll
        for (int ct = 0; ct < 8; ++ct) {
            const float* wrow = W + (size_t)(col_base + ct * 16 + laneM) * XDIM
                                  + ks * 32 + laneK;
            floatx4 w0 = *(const floatx4*)(wrow);
            floatx4 w1 = *(const floatx4*)(wrow + 4);
            bf16x8 bw, bs;
#pragma unroll
            for (int j = 0; j < 4; ++j) {
                bw[j]     = (__bf16)w0[j];
                bw[j + 4] = (__bf16)w1[j];
                bs[j]     = (__bf16)(w0[j] * w0[j]);
                bs[j + 4] = (__bf16)(w1[j] * w1[j]);
            }
#pragma unroll
            for (int rt = 0; rt < 2; ++rt) {
                accM[rt][ct] = __builtin_amdgcn_mfma_f32_16x16x32_bf16(
                                   aM[rt][ks], bw, accM[rt][ct], 0, 0, 0);
                accV[rt][ct] = __builtin_amdgcn_mfma_f32_16x16x32_bf16(
                                   aV[rt][ks], bs, accV[rt][ct], 0, 0, 0);
            }
        }
    }

#pragma unroll
    for (int ct = 0; ct < 8; ++ct) {
        const int col = col_base + ct * 16 + laneM;
        const float bv = bias[col];
#pragma unroll
        for (int rt = 0; rt < 2; ++rt) {
            const int r0 = row_base + rt * 16 + (lane >> 4) * 4;
#pragma unroll
            for (int i = 0; i < 4; ++i) {
                out_mean[(size_t)(r0 + i) * YDIM + col] = accM[rt][ct][i] + bv;
                out_logv[(size_t)(r0 + i) * YDIM + col] = __logf(accV[rt][ct][i]);
            }
        }
    }
}

extern "C" void kernel_launch(void* const* d_in, const int* in_sizes, int n_in,
                              void* d_out, int out_size, void* d_ws, size_t ws_size,
                              hipStream_t stream)
{
    const float* mean   = (const float*)d_in[0];
    const float* logvar = (const float*)d_in[1];
    const float* W      = (const float*)d_in[2];
    const float* bias   = (const float*)d_in[3];

    const int batch = in_sizes[0] / XDIM;   // 131072
    float* out_mean = (float*)d_out;
    float* out_logv = (float*)d_out + (size_t)batch * YDIM;

    const size_t ws_need = (size_t)YDIM * XDIM * sizeof(__bf16) * 2;  // 256 KiB

    if (d_ws != nullptr && ws_size >= ws_need) {
        __bf16* Wb  = (__bf16*)d_ws;
        __bf16* W2b = Wb + (size_t)YDIM * XDIM;
        // one-shot W conversion (stream-ordered before the main kernel)
        hipLaunchKernelGGL(prep_w_kernel, dim3(32), dim3(256), 0, stream,
                           W, Wb, W2b);
        hipLaunchKernelGGL(decoder_mfma_v2, dim3(batch / 32), dim3(256), 0, stream,
                           mean, logvar, Wb, W2b, bias, out_mean, out_logv);
    } else {
        hipLaunchKernelGGL(decoder_mfma_kernel, dim3(batch / 32), dim3(256), 0, stream,
                           mean, logvar, W, bias, out_mean, out_logv);
    }
}